// Round 1
// baseline (445.455 us; speedup 1.0000x reference)
//
#include <hip/hip_runtime.h>

// GroupedQueryAttention: B=2, S=2048, HIDDEN=2048, NH=16, NKV=4, HD=128, G=4
// Pipeline: x->bf16; W->bf16 transposed (NxK); GEMM qkv; V transpose; flash attn; GEMM out.
// Workspace need: ~84 MB bf16 scratch.

#define SEQ    2048
#define HIDDEN 2048
#define NKV    4
#define HD     128

typedef __attribute__((ext_vector_type(8))) short v8s;   // 8 x bf16 (4 VGPRs)
typedef __attribute__((ext_vector_type(4))) float v4f;   // MFMA accumulator

#define MFMA16(a,b,c) __builtin_amdgcn_mfma_f32_16x16x32_bf16((a),(b),(c),0,0,0)

__device__ __forceinline__ ushort f2b(float f){
  unsigned u = __float_as_uint(f);
  u += 0x7fffu + ((u >> 16) & 1u);       // round-to-nearest-even
  return (ushort)(u >> 16);
}

// ---------- fp32 -> bf16, 4 elems/thread ----------
__global__ void k_conv(const float* __restrict__ in, ushort* __restrict__ out, int n){
  int i = (blockIdx.x*256 + threadIdx.x)*4;
  if (i >= n) return;
  float4 f = *(const float4*)(in + i);
  ushort4 u; u.x=f2b(f.x); u.y=f2b(f.y); u.z=f2b(f.z); u.w=f2b(f.w);
  *(ushort4*)(out + i) = u;
}

// ---------- fp32 (rows x cols) -> bf16 (cols x rows), LDS-tiled ----------
__global__ void k_tconv(const float* __restrict__ in, ushort* __restrict__ out,
                        int rows, int cols){
  __shared__ float t[32][33];
  int tx = threadIdx.x & 31, ty = threadIdx.x >> 5;
  int c0 = blockIdx.x*32, r0 = blockIdx.y*32;
#pragma unroll
  for (int i=0;i<4;i++) t[ty+i*8][tx] = in[(size_t)(r0+ty+i*8)*cols + c0+tx];
  __syncthreads();
#pragma unroll
  for (int i=0;i<4;i++) out[(size_t)(c0+ty+i*8)*rows + r0+tx] = f2b(t[tx][ty+i*8]);
}

// ---------- V bf16 (b,s,h,d) -> (b,h,d,s) ----------
__global__ void k_tv(const ushort* __restrict__ vb, ushort* __restrict__ vT){
  __shared__ ushort t[32][33];
  int tx = threadIdx.x & 31, ty = threadIdx.x >> 5;
  int s0 = blockIdx.x*32, d0 = blockIdx.y*32, bh = blockIdx.z;
  int b = bh >> 2, h = bh & 3;
  const ushort* src = vb + (size_t)b*SEQ*512 + h*128;
#pragma unroll
  for (int i=0;i<4;i++) t[ty+i*8][tx] = src[(size_t)(s0+ty+i*8)*512 + d0+tx];
  __syncthreads();
  ushort* dst = vT + (size_t)bh*128*SEQ;
#pragma unroll
  for (int i=0;i<4;i++) dst[(size_t)(d0+ty+i*8)*SEQ + s0+tx] = t[tx][ty+i*8];
}

// ---------- GEMM mainloop (128x128 tile, BK=32, 4 waves, 4x4 MFMA tiles/wave) ----------
#define LDT 48   // padded LDS row stride (elems): 96B = 6x16B aligned, bank-spread

#define GEMM_MAIN(A_, Bt_, K_)                                                        \
  __shared__ ushort sA[128*LDT], sB[128*LDT];                                         \
  const int tid = threadIdx.x, lane = tid & 63, wid = tid >> 6;                       \
  const int wm = wid >> 1, wn = wid & 1, lm = lane & 15, q8 = (lane >> 4)*8;          \
  const int rowB = blockIdx.y*128, colB = blockIdx.x*128;                             \
  v4f acc[4][4] = {};                                                                 \
  for (int k0 = 0; k0 < (K_); k0 += 32){                                              \
    _Pragma("unroll")                                                                 \
    for (int it=0; it<2; it++){                                                       \
      int c = tid + it*256, r = c >> 2, cw = (c & 3)*8;                               \
      *(int4*)(sA + r*LDT + cw) = *(const int4*)((A_)  + (size_t)(rowB+r)*(K_) + k0 + cw); \
      *(int4*)(sB + r*LDT + cw) = *(const int4*)((Bt_) + (size_t)(colB+r)*(K_) + k0 + cw); \
    }                                                                                 \
    __syncthreads();                                                                  \
    v8s af[4], bfr[4];                                                                \
    _Pragma("unroll")                                                                 \
    for (int i=0;i<4;i++){                                                            \
      af[i]  = *(const v8s*)(sA + (wm*64 + i*16 + lm)*LDT + q8);                      \
      bfr[i] = *(const v8s*)(sB + (wn*64 + i*16 + lm)*LDT + q8);                      \
    }                                                                                 \
    _Pragma("unroll")                                                                 \
    for (int i=0;i<4;i++)                                                             \
      _Pragma("unroll")                                                               \
      for (int j=0;j<4;j++) acc[i][j] = MFMA16(af[i], bfr[j], acc[i][j]);             \
    __syncthreads();                                                                  \
  }                                                                                   \
  const int quad = lane >> 4;

// QKV GEMM: M=4096, N=3072(packed q|k|v), K=2048; epilogue routes + bias + bf16
__global__ __launch_bounds__(256) void k_gemm_qkv(
    const ushort* __restrict__ A, const ushort* __restrict__ Bt,
    const float* __restrict__ bq, const float* __restrict__ bk, const float* __restrict__ bv,
    ushort* __restrict__ qb, ushort* __restrict__ kb, ushort* __restrict__ vb){
  GEMM_MAIN(A, Bt, HIDDEN)
#pragma unroll
  for (int i=0;i<4;i++)
#pragma unroll
  for (int j=0;j<4;j++){
    int col = colB + wn*64 + j*16 + lm;
#pragma unroll
    for (int r=0;r<4;r++){
      int row = rowB + wm*64 + i*16 + quad*4 + r;
      float v = acc[i][j][r];
      if (col < 2048)      qb[(size_t)row*2048 + col]        = f2b(v + bq[col]);
      else if (col < 2560) kb[(size_t)row*512 + (col-2048)]  = f2b(v + bk[col-2048]);
      else                 vb[(size_t)row*512 + (col-2560)]  = f2b(v + bv[col-2560]);
    }
  }
}

// Output GEMM: M=4096, N=2048, K=2048; fp32 out + bias
__global__ __launch_bounds__(256) void k_gemm_out(
    const ushort* __restrict__ A, const ushort* __restrict__ Bt,
    const float* __restrict__ bo, float* __restrict__ out){
  GEMM_MAIN(A, Bt, HIDDEN)
#pragma unroll
  for (int i=0;i<4;i++)
#pragma unroll
  for (int j=0;j<4;j++){
    int col = colB + wn*64 + j*16 + lm;
#pragma unroll
    for (int r=0;r<4;r++){
      int row = rowB + wm*64 + i*16 + quad*4 + r;
      out[(size_t)row*2048 + col] = acc[i][j][r] + bo[col];
    }
  }
}

// ---------- Flash attention ----------
// grid (16 q-tiles, 16 heads, 2 batch), 256 thr. Q-frags in regs; K tile + V^T tile
// in LDS; P aliased onto K tile region (per-wave rows), 3 barriers/iter.
#define ATS 136   // LDS row stride: 272B = 17x16B (aligned b128, rows 4 banks apart)

__global__ __launch_bounds__(256) void k_attn(
    const ushort* __restrict__ qb, const ushort* __restrict__ kb,
    const ushort* __restrict__ vT, ushort* __restrict__ Ob){
  __shared__ ushort sK[128*ATS];   // K tile [key][d]; later P [q-row][key] per wave
  __shared__ ushort sV[128*ATS];   // V^T tile [d][key]
  const int tid = threadIdx.x, lane = tid & 63, w = tid >> 6;
  const int lm = lane & 15, quad = lane >> 4, q8 = quad*8;
  const int qt = blockIdx.x, head = blockIdx.y, b = blockIdx.z;
  const int hkv = head >> 2;
  const float C = 0.08838834764831845f * 1.4426950408889634f;  // SCALE * log2(e)

  v8s qf[2][4];
#pragma unroll
  for (int rb=0; rb<2; rb++)
#pragma unroll
    for (int ks=0; ks<4; ks++)
      qf[rb][ks] = *(const v8s*)(qb + (size_t)(b*SEQ + qt*128 + w*32 + rb*16 + lm)*HIDDEN
                                    + head*HD + ks*32 + q8);

  v4f o[2][8] = {};
  v4f m[2], l[2];
#pragma unroll
  for (int r=0;r<4;r++){ m[0][r] = -3e38f; m[1][r] = -3e38f; l[0][r] = 0.f; l[1][r] = 0.f; }

  for (int t=0; t<SEQ/128; t++){
    __syncthreads();                       // prev iter's P/V reads done
    const int kt0 = t*128;
#pragma unroll
    for (int it=0; it<8; it++){
      int c = tid + it*256, r = c >> 4, cw = (c & 15)*8;
      *(int4*)(sK + r*ATS + cw) = *(const int4*)(kb + (size_t)(b*SEQ + kt0 + r)*512 + hkv*HD + cw);
      *(int4*)(sV + r*ATS + cw) = *(const int4*)(vT + (size_t)((b*NKV + hkv)*HD + r)*SEQ + kt0 + cw);
    }
    __syncthreads();

    // S = Q K^T (raw, scale folded into exp)
    v4f sacc[2][8] = {};
#pragma unroll
    for (int ct=0; ct<8; ct++){
      v8s kf[4];
#pragma unroll
      for (int ks=0; ks<4; ks++) kf[ks] = *(const v8s*)(sK + (ct*16 + lm)*ATS + ks*32 + q8);
#pragma unroll
      for (int rb=0; rb<2; rb++)
#pragma unroll
        for (int ks=0; ks<4; ks++) sacc[rb][ct] = MFMA16(qf[rb][ks], kf[ks], sacc[rb][ct]);
    }
    __syncthreads();                       // all waves done reading sK before P clobbers it

    // online softmax (rows live in quad's 16 lanes; reduce with width-16 shuffles)
#pragma unroll
    for (int rb=0; rb<2; rb++){
      v4f mx = m[rb];
#pragma unroll
      for (int ct=0; ct<8; ct++)
#pragma unroll
        for (int r=0;r<4;r++) mx[r] = fmaxf(mx[r], sacc[rb][ct][r]);
#pragma unroll
      for (int off=8; off>0; off>>=1)
#pragma unroll
        for (int r=0;r<4;r++) mx[r] = fmaxf(mx[r], __shfl_xor(mx[r], off, 16));
      v4f alpha, rs;
#pragma unroll
      for (int r=0;r<4;r++){ alpha[r] = __builtin_amdgcn_exp2f((m[rb][r]-mx[r])*C); rs[r] = 0.f; }
      m[rb] = mx;
#pragma unroll
      for (int ct=0; ct<8; ct++)
#pragma unroll
        for (int r=0;r<4;r++){
          float p = __builtin_amdgcn_exp2f((sacc[rb][ct][r]-mx[r])*C);
          rs[r] += p;
          sK[(w*32 + rb*16 + quad*4 + r)*ATS + ct*16 + lm] = f2b(p);   // P, A-layout rows
        }
#pragma unroll
      for (int off=8; off>0; off>>=1)
#pragma unroll
        for (int r=0;r<4;r++) rs[r] += __shfl_xor(rs[r], off, 16);
#pragma unroll
      for (int r=0;r<4;r++) l[rb][r] = l[rb][r]*alpha[r] + rs[r];
#pragma unroll
      for (int ct=0; ct<8; ct++)
#pragma unroll
        for (int r=0;r<4;r++) o[rb][ct][r] *= alpha[r];
    }

    // O += P V   (P read back from per-wave LDS region; wave-local, no barrier)
    v8s pa[2][4];
#pragma unroll
    for (int rb=0; rb<2; rb++)
#pragma unroll
      for (int ks=0; ks<4; ks++)
        pa[rb][ks] = *(const v8s*)(sK + (w*32 + rb*16 + lm)*ATS + ks*32 + q8);
#pragma unroll
    for (int ct=0; ct<8; ct++){
      v8s vf[4];
#pragma unroll
      for (int ks=0; ks<4; ks++) vf[ks] = *(const v8s*)(sV + (ct*16 + lm)*ATS + ks*32 + q8);
#pragma unroll
      for (int rb=0; rb<2; rb++)
#pragma unroll
        for (int ks=0; ks<4; ks++) o[rb][ct] = MFMA16(pa[rb][ks], vf[ks], o[rb][ct]);
    }
  }

  // epilogue: normalize, write bf16 O
#pragma unroll
  for (int rb=0; rb<2; rb++){
    v4f inv;
#pragma unroll
    for (int r=0;r<4;r++) inv[r] = 1.0f / l[rb][r];
#pragma unroll
    for (int ct=0; ct<8; ct++)
#pragma unroll
      for (int r=0;r<4;r++){
        int row = b*SEQ + qt*128 + w*32 + rb*16 + quad*4 + r;
        int col = head*HD + ct*16 + lm;
        Ob[(size_t)row*HIDDEN + col] = f2b(o[rb][ct][r]*inv[r]);
      }
  }
}

extern "C" void kernel_launch(void* const* d_in, const int* in_sizes, int n_in,
                              void* d_out, int out_size, void* d_ws, size_t ws_size,
                              hipStream_t stream){
  const float* x  = (const float*)d_in[0];
  const float* Wq = (const float*)d_in[1];
  const float* bq = (const float*)d_in[2];
  const float* Wk = (const float*)d_in[3];
  const float* bk = (const float*)d_in[4];
  const float* Wv = (const float*)d_in[5];
  const float* bv = (const float*)d_in[6];
  const float* Wo = (const float*)d_in[7];
  const float* bo = (const float*)d_in[8];
  float* out = (float*)d_out;

  // workspace layout (bf16 elems): 41,943,040 ushorts = 83.9 MB
  ushort* xb  = (ushort*)d_ws;        // 4096x2048
  ushort* Wt  = xb  + 8388608;        // 3072x2048  (Wq^T | Wk^T | Wv^T)
  ushort* Wto = Wt  + 6291456;        // 2048x2048  (Wo^T)
  ushort* qb  = Wto + 4194304;        // 4096x2048
  ushort* kb  = qb  + 8388608;        // 4096x512
  ushort* vb  = kb  + 2097152;        // 4096x512
  ushort* vT  = vb  + 2097152;        // (b,h,d,s) 2x4x128x2048
  ushort* Ob  = vT  + 2097152;        // 4096x2048

  k_conv <<<8192, 256, 0, stream>>>(x, xb, 8388608);
  k_tconv<<<dim3(64,64), 256, 0, stream>>>(Wq, Wt, 2048, 2048);
  k_tconv<<<dim3(16,64), 256, 0, stream>>>(Wk, Wt + 4194304, 2048, 512);
  k_tconv<<<dim3(16,64), 256, 0, stream>>>(Wv, Wt + 5242880, 2048, 512);
  k_tconv<<<dim3(64,64), 256, 0, stream>>>(Wo, Wto, 2048, 2048);
  k_gemm_qkv<<<dim3(24,32), 256, 0, stream>>>(xb, Wt, bq, bk, bv, qb, kb, vb);
  k_tv  <<<dim3(64,4,8), 256, 0, stream>>>(vb, vT);
  k_attn<<<dim3(16,16,2), 256, 0, stream>>>(qb, kb, vT, Ob);
  k_gemm_out<<<dim3(16,32), 256, 0, stream>>>(Ob, Wto, bo, out);
}

// Round 2
// 380.741 us; speedup vs baseline: 1.1700x; 1.1700x over previous
//
#include <hip/hip_runtime.h>

// GroupedQueryAttention: B=2, S=2048, HIDDEN=2048, NH=16, NKV=4, HD=128, G=4
// R2: GEMMs use global_load_lds(16B) staging w/ unpadded 128x32 tiles (m97 ladder);
//     attention computes S^T (A=K,B=Q) -> lane-local softmax (2 shuffles), packed
//     b64 P-store, alpha/l transposed to C-layout via 8 bpermutes/iter.

#define SEQ    2048
#define HIDDEN 2048
#define NKV    4
#define HD     128

typedef __attribute__((ext_vector_type(8))) short v8s;   // 8 x bf16 (4 VGPRs)
typedef __attribute__((ext_vector_type(4))) float v4f;   // MFMA accumulator

#define MFMA16(a,b,c) __builtin_amdgcn_mfma_f32_16x16x32_bf16((a),(b),(c),0,0,0)

__device__ __forceinline__ ushort f2b(float f){
  unsigned u = __float_as_uint(f);
  u += 0x7fffu + ((u >> 16) & 1u);       // round-to-nearest-even
  return (ushort)(u >> 16);
}

__device__ __forceinline__ void gload16(const void* g, void* l){
  __builtin_amdgcn_global_load_lds((const __attribute__((address_space(1))) void*)g,
                                   (__attribute__((address_space(3))) void*)l, 16, 0, 0);
}

// ---------- fp32 -> bf16, 4 elems/thread ----------
__global__ void k_conv(const float* __restrict__ in, ushort* __restrict__ out, int n){
  int i = (blockIdx.x*256 + threadIdx.x)*4;
  if (i >= n) return;
  float4 f = *(const float4*)(in + i);
  ushort4 u; u.x=f2b(f.x); u.y=f2b(f.y); u.z=f2b(f.z); u.w=f2b(f.w);
  *(ushort4*)(out + i) = u;
}

// ---------- fp32 (rows x cols) -> bf16 (cols x rows), LDS-tiled ----------
__global__ void k_tconv(const float* __restrict__ in, ushort* __restrict__ out,
                        int rows, int cols){
  __shared__ float t[32][33];
  int tx = threadIdx.x & 31, ty = threadIdx.x >> 5;
  int c0 = blockIdx.x*32, r0 = blockIdx.y*32;
#pragma unroll
  for (int i=0;i<4;i++) t[ty+i*8][tx] = in[(size_t)(r0+ty+i*8)*cols + c0+tx];
  __syncthreads();
#pragma unroll
  for (int i=0;i<4;i++) out[(size_t)(c0+ty+i*8)*rows + r0+tx] = f2b(t[tx][ty+i*8]);
}

// ---------- V bf16 (b,s,h,d) -> (b,h,d,s) ----------
__global__ void k_tv(const ushort* __restrict__ vb, ushort* __restrict__ vT){
  __shared__ ushort t[32][33];
  int tx = threadIdx.x & 31, ty = threadIdx.x >> 5;
  int s0 = blockIdx.x*32, d0 = blockIdx.y*32, bh = blockIdx.z;
  int b = bh >> 2, h = bh & 3;
  const ushort* src = vb + (size_t)b*SEQ*512 + h*128;
#pragma unroll
  for (int i=0;i<4;i++) t[ty+i*8][tx] = src[(size_t)(s0+ty+i*8)*512 + d0+tx];
  __syncthreads();
  ushort* dst = vT + (size_t)bh*128*SEQ;
#pragma unroll
  for (int i=0;i<4;i++) dst[(size_t)(d0+ty+i*8)*SEQ + s0+tx] = t[tx][ty+i*8];
}

// ---------- GEMM mainloop: 128x128 tile, BK=32, global_load_lds staging ----------
// LDS tiles unpadded [128][32]; staging order = lane-contiguous (wave-uniform base
// + lane*16 requirement of global_load_lds). Frag reads at stride 32 are bank-balanced.

#define GEMM_MAIN(A_, Bt_, K_)                                                        \
  __shared__ ushort sA[128*32], sB[128*32];                                           \
  const int tid = threadIdx.x, lane = tid & 63, wid = tid >> 6;                       \
  const int wm = wid >> 1, wn = wid & 1, lm = lane & 15, q8 = (lane >> 4)*8;          \
  const int rowB = blockIdx.y*128, colB = blockIdx.x*128;                             \
  v4f acc[4][4] = {};                                                                 \
  for (int k0 = 0; k0 < (K_); k0 += 32){                                              \
    _Pragma("unroll")                                                                 \
    for (int it=0; it<2; it++){                                                       \
      int c = tid + it*256;                                                           \
      gload16((A_)  + (size_t)(rowB + (c>>2))*(K_) + k0 + (c&3)*8, (char*)sA + c*16); \
      gload16((Bt_) + (size_t)(colB + (c>>2))*(K_) + k0 + (c&3)*8, (char*)sB + c*16); \
    }                                                                                 \
    __syncthreads();                                                                  \
    v8s af[4], bfr[4];                                                                \
    _Pragma("unroll")                                                                 \
    for (int i=0;i<4;i++){                                                            \
      af[i]  = *(const v8s*)(sA + (wm*64 + i*16 + lm)*32 + q8);                       \
      bfr[i] = *(const v8s*)(sB + (wn*64 + i*16 + lm)*32 + q8);                       \
    }                                                                                 \
    _Pragma("unroll")                                                                 \
    for (int i=0;i<4;i++)                                                             \
      _Pragma("unroll")                                                               \
      for (int j=0;j<4;j++) acc[i][j] = MFMA16(af[i], bfr[j], acc[i][j]);             \
    __syncthreads();                                                                  \
  }                                                                                   \
  const int quad = lane >> 4;

// QKV GEMM: M=4096, N=3072(packed q|k|v), K=2048; epilogue routes + bias + bf16
__global__ __launch_bounds__(256) void k_gemm_qkv(
    const ushort* __restrict__ A, const ushort* __restrict__ Bt,
    const float* __restrict__ bq, const float* __restrict__ bk, const float* __restrict__ bv,
    ushort* __restrict__ qb, ushort* __restrict__ kb, ushort* __restrict__ vb){
  GEMM_MAIN(A, Bt, HIDDEN)
#pragma unroll
  for (int i=0;i<4;i++)
#pragma unroll
  for (int j=0;j<4;j++){
    int col = colB + wn*64 + j*16 + lm;
#pragma unroll
    for (int r=0;r<4;r++){
      int row = rowB + wm*64 + i*16 + quad*4 + r;
      float v = acc[i][j][r];
      if (col < 2048)      qb[(size_t)row*2048 + col]        = f2b(v + bq[col]);
      else if (col < 2560) kb[(size_t)row*512 + (col-2048)]  = f2b(v + bk[col-2048]);
      else                 vb[(size_t)row*512 + (col-2560)]  = f2b(v + bv[col-2560]);
    }
  }
}

// Output GEMM: M=4096, N=2048, K=2048; fp32 out + bias
__global__ __launch_bounds__(256) void k_gemm_out(
    const ushort* __restrict__ A, const ushort* __restrict__ Bt,
    const float* __restrict__ bo, float* __restrict__ out){
  GEMM_MAIN(A, Bt, HIDDEN)
#pragma unroll
  for (int i=0;i<4;i++)
#pragma unroll
  for (int j=0;j<4;j++){
    int col = colB + wn*64 + j*16 + lm;
#pragma unroll
    for (int r=0;r<4;r++){
      int row = rowB + wm*64 + i*16 + quad*4 + r;
      out[(size_t)row*2048 + col] = acc[i][j][r] + bo[col];
    }
  }
}

// ---------- Flash attention (S^T formulation) ----------
// grid (16 q-tiles, 16 heads, 2 batch), 256 thr. Q-frags in regs; K tile + V^T tile
// in LDS. S^T = MFMA(A=K, B=Q): lane holds col=qrow(lm), rows=key(quad*4+r) ->
// softmax is in-lane + 2 shuffles; P stored as packed ds_write_b64 into sK (aliased,
// wave-local rows), read back as A-operand for PV. alpha/l transposed to C-layout
// via __shfl for the O-rescale.
#define ATS 136   // LDS row stride: 272B (16B-aligned, rows 4 banks apart)

__global__ __launch_bounds__(256) void k_attn(
    const ushort* __restrict__ qb, const ushort* __restrict__ kb,
    const ushort* __restrict__ vT, ushort* __restrict__ Ob){
  __shared__ ushort sK[128*ATS];   // K tile [key][d]; later P [qrow][key]
  __shared__ ushort sV[128*ATS];   // V^T tile [d][key]
  const int tid = threadIdx.x, lane = tid & 63, w = tid >> 6;
  const int lm = lane & 15, quad = lane >> 4, q8 = quad*8;
  const int qt = blockIdx.x, head = blockIdx.y, b = blockIdx.z;
  const int hkv = head >> 2;
  const float C = 0.08838834764831845f * 1.4426950408889634f;  // SCALE * log2(e)

  // Q fragments (B-operand: row = qrow rb*16+lm, k = d)
  v8s qf[2][4];
#pragma unroll
  for (int rb=0; rb<2; rb++)
#pragma unroll
    for (int ks=0; ks<4; ks++)
      qf[rb][ks] = *(const v8s*)(qb + (size_t)(b*SEQ + qt*128 + w*32 + rb*16 + lm)*HIDDEN
                                    + head*HD + ks*32 + q8);

  v4f o[2][8] = {};                 // [qrow-tile][d-tile], C-layout
  float mreg[2] = {-3e38f, -3e38f};
  float lreg[2] = {0.f, 0.f};

  for (int t=0; t<SEQ/128; t++){
    __syncthreads();                       // prev iter's P/V reads done
    const int kt0 = t*128;
#pragma unroll
    for (int it=0; it<8; it++){
      int c = tid + it*256, r = c >> 4, cw = (c & 15)*8;
      *(int4*)(sK + r*ATS + cw) = *(const int4*)(kb + (size_t)(b*SEQ + kt0 + r)*512 + hkv*HD + cw);
      *(int4*)(sV + r*ATS + cw) = *(const int4*)(vT + (size_t)((b*NKV + hkv)*HD + r)*SEQ + kt0 + cw);
    }
    __syncthreads();

    // S^T: sacc[rb][ct], m=key (ct over 8 tiles), n=qrow (rb over 2 tiles)
    v4f sacc[2][8] = {};
#pragma unroll
    for (int ct=0; ct<8; ct++){
      v8s kf[4];
#pragma unroll
      for (int ks=0; ks<4; ks++) kf[ks] = *(const v8s*)(sK + (ct*16 + lm)*ATS + ks*32 + q8);
#pragma unroll
      for (int rb=0; rb<2; rb++)
#pragma unroll
        for (int ks=0; ks<4; ks++) sacc[rb][ct] = MFMA16(kf[ks], qf[rb][ks], sacc[rb][ct]);
    }
    __syncthreads();                       // all waves done reading sK; sK becomes P

    // online softmax: lane's qrow = rb*16+lm; keys ct*16+quad*4+r (32 in-lane)
    float alpha[2];
#pragma unroll
    for (int rb=0; rb<2; rb++){
      float mx = mreg[rb];
#pragma unroll
      for (int ct=0; ct<8; ct++)
#pragma unroll
        for (int r=0;r<4;r++) mx = fmaxf(mx, sacc[rb][ct][r]);
      mx = fmaxf(mx, __shfl_xor(mx, 16));
      mx = fmaxf(mx, __shfl_xor(mx, 32));
      alpha[rb] = __builtin_amdgcn_exp2f((mreg[rb]-mx)*C);
      mreg[rb] = mx;
      float rs = 0.f;
      ushort* prow = sK + (size_t)(w*32 + rb*16 + lm)*ATS;
#pragma unroll
      for (int ct=0; ct<8; ct++){
        float p0 = __builtin_amdgcn_exp2f((sacc[rb][ct][0]-mx)*C);
        float p1 = __builtin_amdgcn_exp2f((sacc[rb][ct][1]-mx)*C);
        float p2 = __builtin_amdgcn_exp2f((sacc[rb][ct][2]-mx)*C);
        float p3 = __builtin_amdgcn_exp2f((sacc[rb][ct][3]-mx)*C);
        rs += (p0+p1)+(p2+p3);
        uint2 pk;
        pk.x = (unsigned)f2b(p0) | ((unsigned)f2b(p1) << 16);
        pk.y = (unsigned)f2b(p2) | ((unsigned)f2b(p3) << 16);
        *(uint2*)(prow + ct*16 + quad*4) = pk;   // P[qrow][key], 4 keys packed
      }
      rs += __shfl_xor(rs, 16);
      rs += __shfl_xor(rs, 32);
      lreg[rb] = lreg[rb]*alpha[rb] + rs;
    }

    // rescale O: alpha lives at lanes lm=qrow; O rows are quad*4+r -> transpose via shfl
#pragma unroll
    for (int rbo=0; rbo<2; rbo++)
#pragma unroll
      for (int r=0;r<4;r++){
        float a = __shfl(alpha[rbo], (lane & 48) + quad*4 + r);
#pragma unroll
        for (int dt=0; dt<8; dt++) o[rbo][dt][r] *= a;
      }

    // O += P V   (pa: A-operand, wave-local P rows; vf: B-operand from sV)
    v8s pa[2][4];
#pragma unroll
    for (int rbo=0; rbo<2; rbo++)
#pragma unroll
      for (int ks2=0; ks2<4; ks2++)
        pa[rbo][ks2] = *(const v8s*)(sK + (size_t)(w*32 + rbo*16 + lm)*ATS + ks2*32 + q8);
#pragma unroll
    for (int dt=0; dt<8; dt++){
      v8s vf[4];
#pragma unroll
      for (int ks2=0; ks2<4; ks2++) vf[ks2] = *(const v8s*)(sV + (dt*16 + lm)*ATS + ks2*32 + q8);
#pragma unroll
      for (int rbo=0; rbo<2; rbo++)
#pragma unroll
        for (int ks2=0; ks2<4; ks2++) o[rbo][dt] = MFMA16(pa[rbo][ks2], vf[ks2], o[rbo][dt]);
    }
  }

  // epilogue: transpose l to C-layout, normalize, write bf16 O
#pragma unroll
  for (int rbo=0; rbo<2; rbo++){
    float inv[4];
#pragma unroll
    for (int r=0;r<4;r++) inv[r] = 1.0f / __shfl(lreg[rbo], (lane & 48) + quad*4 + r);
#pragma unroll
    for (int dt=0; dt<8; dt++)
#pragma unroll
      for (int r=0;r<4;r++){
        int row = b*SEQ + qt*128 + w*32 + rbo*16 + quad*4 + r;
        int col = head*HD + dt*16 + lm;
        Ob[(size_t)row*HIDDEN + col] = f2b(o[rbo][dt][r]*inv[r]);
      }
  }
}

extern "C" void kernel_launch(void* const* d_in, const int* in_sizes, int n_in,
                              void* d_out, int out_size, void* d_ws, size_t ws_size,
                              hipStream_t stream){
  const float* x  = (const float*)d_in[0];
  const float* Wq = (const float*)d_in[1];
  const float* bq = (const float*)d_in[2];
  const float* Wk = (const float*)d_in[3];
  const float* bk = (const float*)d_in[4];
  const float* Wv = (const float*)d_in[5];
  const float* bv = (const float*)d_in[6];
  const float* Wo = (const float*)d_in[7];
  const float* bo = (const float*)d_in[8];
  float* out = (float*)d_out;

  // workspace layout (bf16 elems): 41,943,040 ushorts = 83.9 MB
  ushort* xb  = (ushort*)d_ws;        // 4096x2048
  ushort* Wt  = xb  + 8388608;        // 3072x2048  (Wq^T | Wk^T | Wv^T)
  ushort* Wto = Wt  + 6291456;        // 2048x2048  (Wo^T)
  ushort* qb  = Wto + 4194304;        // 4096x2048
  ushort* kb  = qb  + 8388608;        // 4096x512
  ushort* vb  = kb  + 2097152;        // 4096x512
  ushort* vT  = vb  + 2097152;        // (b,h,d,s) 2x4x128x2048
  ushort* Ob  = vT  + 2097152;        // 4096x2048

  k_conv <<<8192, 256, 0, stream>>>(x, xb, 8388608);
  k_tconv<<<dim3(64,64), 256, 0, stream>>>(Wq, Wt, 2048, 2048);
  k_tconv<<<dim3(16,64), 256, 0, stream>>>(Wk, Wt + 4194304, 2048, 512);
  k_tconv<<<dim3(16,64), 256, 0, stream>>>(Wv, Wt + 5242880, 2048, 512);
  k_tconv<<<dim3(64,64), 256, 0, stream>>>(Wo, Wto, 2048, 2048);
  k_gemm_qkv<<<dim3(24,32), 256, 0, stream>>>(xb, Wt, bq, bk, bv, qb, kb, vb);
  k_tv  <<<dim3(64,4,8), 256, 0, stream>>>(vb, vT);
  k_attn<<<dim3(16,16,2), 256, 0, stream>>>(qb, kb, vT, Ob);
  k_gemm_out<<<dim3(16,32), 256, 0, stream>>>(Ob, Wto, bo, out);
}